// Round 7
// baseline (213.615 us; speedup 1.0000x reference)
//
#include <hip/hip_runtime.h>
#include <hip/hip_bf16.h>

// ---------------------------------------------------------------------------
// GraphSAGE 2-layer: h = relu(mean_agg(x) @ W1l^T + b1 + x @ W1r^T)
//                    out = mean_agg(h) @ W2l^T + b2 + h @ W2r^T
// N=50000, E=800000, C: 128 -> 256 -> 2.
// Session R6: atomic-free full-row GEMM.
//  R5 evidence: global-atomic epilogue costs ~50 MB of HBM RMW traffic
//  (WRITE 26->45->81 MB tracks atomic usage); scattered direct loads with
//  disjoint waves defeat cache reuse (133 MB @ 1.95 TB/s = 68 us).
//  New gemm: 64 rows x 256 cols per block (782 blocks, 256 thr, 4 col-waves).
//   - A direct-loaded: all 4 waves read the SAME fragments -> L1-shared.
//   - B LDS-staged (36.8 KB only) -> 4 blocks/CU.
//   - Epilogue: shuffle-reduce -> 1 KB LDS pr combine -> PLAIN float2 stores.
//     No global atomics; p2/rs memset eliminated (memset now 2 KB bcnt only).
// Pipeline (5 dispatches): memset(bcnt) -> scatter_conv -> sort_gather
// -> gemm1_fused -> fin_bucket.
// Failed-experiment ledger:
//  - R13(prev): 1024-thr GEMM, 62 KB LDS -> 2 blk/CU. Regressed.
//  - R14(prev): last-block-combines w/ __threadfence. Regressed hard.
//  - R1: 512-thr full-width GEMM, 55 KB LDS -> 2 blk/CU. Mixed (best total
//    179.1 though: its LDS-combine epilogue avoided atomic traffic).
//  - R3/R4: reg-prefetch K-loop (VGPR 136 -> 3 waves/SIMD) + XCD swizzle:
//    182 -> 191. Reverted.
//  - R5: LDS-free direct-load gemm + atomics: 68 us gemm, 133 MB traffic,
//    total 209.6. Reverted.
//  - Lesson: replay-pass durations are distorted; atomic WRITE traffic and
//    totals are ground truth.
// ---------------------------------------------------------------------------

#define IN_C 128
#define HID_C 256
#define BKT_SHIFT 7
#define BKT_W 128            // dsts per bucket
#define CAP 3072             // bucket slot capacity (mean 2048, sigma 45)

typedef __attribute__((ext_vector_type(8))) short short8;   // 8 bf16 (4 VGPRs)
typedef __attribute__((ext_vector_type(4))) float f32x4;    // MFMA accumulator

static __device__ __forceinline__ unsigned short f2b(float f) {
    __hip_bfloat16 h = __float2bfloat16(f);
    return *(unsigned short*)&h;
}
static __device__ __forceinline__ float b2f(unsigned short u) {
    unsigned v = ((unsigned)u) << 16;
    return *(float*)&v;
}

// ---- fused conversions + direct bucket scatter -----------------------------
// Blocks [0, xblk): fill right half of A with bf16(x), float4->uint2.
// Blocks [xblk, xblk+32): Bg = bf16([W1l | W1r]), float4->ushort4.
// Blocks [xblk+32, ...): scatter 2048 edges/block into fixed bucket slots.
__global__ __launch_bounds__(512) void scatter_conv(
    const float* __restrict__ x, unsigned int* __restrict__ Abf,
    const float* __restrict__ w1l, const float* __restrict__ w1r,
    unsigned short* __restrict__ Bg,
    const int* __restrict__ ei, int* __restrict__ bcnt,
    unsigned int* __restrict__ binned,
    int nquads /* N*32 */, int xblk, int E_) {
    __shared__ int hist[512];
    __shared__ int lbase[512];
    const int tid = threadIdx.x;
    if (blockIdx.x < xblk) {
        int t = blockIdx.x * 512 + tid;          // one float4 (4 elems) per thr
        if (t >= nquads) return;
        float4 v = *(const float4*)&x[(size_t)t * 4];
        uint2 o;
        o.x = ((unsigned)f2b(v.y) << 16) | f2b(v.x);
        o.y = ((unsigned)f2b(v.w) << 16) | f2b(v.z);
        int node = t >> 5, g = t & 31;           // 32 quads per 128-float row
        *(uint2*)&Abf[(size_t)node * 128 + 64 + g * 2] = o;
    } else if (blockIdx.x < xblk + 32) {
        int idx4 = (blockIdx.x - xblk) * 512 + tid;   // 16384 float4 groups
        int o = idx4 >> 6, k4 = (idx4 & 63) * 4;
        const float* srcp = (k4 < IN_C) ? &w1l[o * IN_C + k4]
                                        : &w1r[o * IN_C + (k4 - IN_C)];
        float4 f = *(const float4*)srcp;
        ushort4 s;
        s.x = f2b(f.x); s.y = f2b(f.y); s.z = f2b(f.z); s.w = f2b(f.w);
        *(ushort4*)&Bg[(size_t)idx4 * 4] = s;
    } else {
        const int e0 = (blockIdx.x - xblk - 32) * 2048;
        hist[tid] = 0;
        __syncthreads();
        int dreg[4];
#pragma unroll
        for (int j = 0; j < 4; ++j) {
            int e = e0 + j * 512 + tid;
            dreg[j] = (e < E_) ? ei[E_ + e] : -1;
            if (dreg[j] >= 0) atomicAdd(&hist[dreg[j] >> BKT_SHIFT], 1);
        }
        __syncthreads();
        {
            int c = hist[tid];
            lbase[tid] = c ? tid * CAP + atomicAdd(&bcnt[tid], c) : 0;
            hist[tid] = 0;   // reuse as local cursor
        }
        __syncthreads();
#pragma unroll
        for (int j = 0; j < 4; ++j) {
            int e = e0 + j * 512 + tid;
            if (dreg[j] >= 0) {
                int d = dreg[j];
                int b = d >> BKT_SHIFT;
                int pos = lbase[b] + atomicAdd(&hist[b], 1);
                if (pos < b * CAP + CAP)   // +22 sigma guard, never taken
                    binned[pos] = ((unsigned)ei[e] << BKT_SHIFT) |
                                  (unsigned)(d & (BKT_W - 1));
            }
        }
    }
}

// ---- per-bucket LDS sort + immediate neighbor gather -----------------------
// Also persists the sorted src list (ushort, in-place over binned) and the
// per-node segment offsets for the atomic-free fin_bucket.

__global__ __launch_bounds__(1024) void sort_gather(
    unsigned int* __restrict__ binned, const int* __restrict__ bcnt,
    const uint4* __restrict__ abf4c, uint4* __restrict__ Abf4,
    int* __restrict__ deg, int* __restrict__ boffs, int n) {
    __shared__ unsigned int ebuf[CAP];        // 12 KB
    __shared__ unsigned short sbuf[CAP];      // 6 KB
    __shared__ int hist[BKT_W];
    __shared__ int offs[BKT_W];
    __shared__ int cur[BKT_W];
    const int tid = threadIdx.x;
    const int lane = tid & 63;
    const int bkt = blockIdx.x;
    const int gbase = bkt * CAP;
    int cnt = bcnt[bkt];
    if (cnt > CAP) cnt = CAP;

    if (tid < BKT_W) hist[tid] = 0;
    {   // vectorized ebuf fill (binned+gbase is 16B aligned: CAP*4 = 12 KB)
        const int cnt4 = cnt >> 2;
        const uint4* b4 = (const uint4*)(binned + gbase);
        uint4* e4 = (uint4*)ebuf;
        for (int i = tid; i < cnt4; i += 1024) e4[i] = b4[i];
        for (int i = cnt4 * 4 + tid; i < cnt; i += 1024)
            ebuf[i] = binned[gbase + i];
    }
    __syncthreads();
    for (int i = tid; i < cnt; i += 1024)
        atomicAdd(&hist[ebuf[i] & (BKT_W - 1)], 1);
    __syncthreads();
    if (tid < 64) {   // single-wave scan of 128 counts, 2/lane
        int h0 = hist[lane * 2], h1 = hist[lane * 2 + 1];
        int s = h0 + h1;
        int incl = s;
#pragma unroll
        for (int off = 1; off < 64; off <<= 1) {
            int t = __shfl_up(incl, off);
            if (lane >= off) incl += t;
        }
        int excl = incl - s;
        offs[lane * 2] = excl;          cur[lane * 2] = excl;
        offs[lane * 2 + 1] = excl + h0; cur[lane * 2 + 1] = excl + h0;
    }
    __syncthreads();
    for (int i = tid; i < cnt; i += 1024) {
        unsigned int pk = ebuf[i];
        int pos = atomicAdd(&cur[pk & (BKT_W - 1)], 1);
        sbuf[pos] = (unsigned short)(pk >> BKT_SHIFT);   // src (< 65536)
    }
    if (tid < BKT_W) {
        int node = bkt * BKT_W + tid;
        if (node < n) { deg[node] = hist[tid]; boffs[node] = offs[tid]; }
    }
    __syncthreads();

    // persist sorted src list over our own (fully consumed) binned region;
    // packed 2 ushorts per 4B store. Overlaps with the gather phase below.
    {
        unsigned int* so = (unsigned int*)(binned + gbase);
        const int half = (cnt + 1) >> 1;
        for (int i = tid; i < half; i += 1024) {
            unsigned lo = sbuf[i * 2];
            unsigned hi = (i * 2 + 1 < cnt) ? sbuf[i * 2 + 1] : 0u;
            so[i] = lo | (hi << 16);
        }
    }

    // gather phase: wave wv handles local dsts [wv*8, wv*8+8)
    const int wv = tid >> 6;
    const int ep = lane >> 4;
    const int pos = lane & 15;
    for (int ld = wv * 8; ld < wv * 8 + 8; ++ld) {
        int node = bkt * BKT_W + ld;
        if (node >= n) break;
        int beg = offs[ld], end = offs[ld] + hist[ld];
        float s[8] = {0.f, 0.f, 0.f, 0.f, 0.f, 0.f, 0.f, 0.f};
        for (int e = beg; e < end; e += 16) {
#pragma unroll
            for (int g = 0; g < 4; ++g) {       // 4 uint4 loads in flight
                int eg = e + g * 4 + ep;
                if (eg < end) {
                    int src = sbuf[eg];
                    // right half of Abf row (== bf16(x) for this src)
                    uint4 u = abf4c[(size_t)src * 32 + 16 + pos];
                    s[0] += b2f(u.x & 0xffff); s[1] += b2f(u.x >> 16);
                    s[2] += b2f(u.y & 0xffff); s[3] += b2f(u.y >> 16);
                    s[4] += b2f(u.z & 0xffff); s[5] += b2f(u.z >> 16);
                    s[6] += b2f(u.w & 0xffff); s[7] += b2f(u.w >> 16);
                }
            }
        }
#pragma unroll
        for (int i = 0; i < 8; ++i) {
            s[i] += __shfl_xor(s[i], 16);
            s[i] += __shfl_xor(s[i], 32);
        }
        if (ep == 0) {
            float inv = 1.0f / (float)max(end - beg, 1);
            uint4 o;
            o.x = ((unsigned)f2b(s[1] * inv) << 16) | f2b(s[0] * inv);
            o.y = ((unsigned)f2b(s[3] * inv) << 16) | f2b(s[2] * inv);
            o.z = ((unsigned)f2b(s[5] * inv) << 16) | f2b(s[4] * inv);
            o.w = ((unsigned)f2b(s[7] * inv) << 16) | f2b(s[6] * inv);
            Abf4[(size_t)node * 32 + pos] = o;   // left half of A row
        }
    }
}

// ---- Layer-1 GEMM + fused layer-2 projection -------------------------------
// 64 rows x 256 cols per block, 782 blocks, 256 thr (4 col-waves).
// A direct-loaded (all 4 waves share the same fragments -> L1 hit);
// B staged in LDS (36.8 KB -> 4 blocks/CU). Epilogue: shuffle reduce ->
// 1 KB LDS pr cross-wave combine -> plain float2 stores. No atomics.

#define LSTR 72

__global__ __launch_bounds__(256, 4) void gemm1_fused(
    const unsigned short* __restrict__ Abf, const unsigned short* __restrict__ Bg,
    const float* __restrict__ b1, const float* __restrict__ w2l,
    const float* __restrict__ w2r, float2* __restrict__ p2g,
    float2* __restrict__ rsg, int nn) {
    __shared__ short Bs[256 * LSTR];          // 36.8 KB

    const int tid = threadIdx.x;
    const int lane = tid & 63;
    const int wn = tid >> 6;                  // 0..3 col-wave
    const int row0 = blockIdx.x * 64;
    const int quad = lane >> 4;     // 0..3
    const int l16 = lane & 15;

    // A fragment pointers (shared across all 4 waves -> L1 reuse)
    const unsigned short* ap[4];
#pragma unroll
    for (int mt = 0; mt < 4; ++mt) {
        int ar = row0 + mt * 16 + l16;
        if (ar >= nn) ar = nn - 1;
        ap[mt] = Abf + (size_t)ar * 256 + quad * 8;
    }

    f32x4 acc[4][4];
#pragma unroll
    for (int i = 0; i < 4; ++i)
#pragma unroll
        for (int j = 0; j < 4; ++j) acc[i][j] = (f32x4){0.f, 0.f, 0.f, 0.f};

    for (int k0 = 0; k0 < 256; k0 += 64) {
        // stage B: thread tid owns B row (=col) tid, 64 shorts (128 B)
        const uint4* gb = (const uint4*)(Bg + (size_t)tid * 256 + k0);
        uint4 r0 = gb[0], r1 = gb[1], r2 = gb[2], r3 = gb[3];
        uint4 r4 = gb[4], r5 = gb[5], r6 = gb[6], r7 = gb[7];
        __syncthreads();
        uint4* lb = (uint4*)&Bs[tid * LSTR];
        lb[0] = r0; lb[1] = r1; lb[2] = r2; lb[3] = r3;
        lb[4] = r4; lb[5] = r5; lb[6] = r6; lb[7] = r7;
        __syncthreads();

#pragma unroll
        for (int kb = 0; kb < 2; ++kb) {
            short8 af[4], bf[4];
#pragma unroll
            for (int mt = 0; mt < 4; ++mt)
                af[mt] = *(const short8*)(ap[mt] + k0 + kb * 32);
#pragma unroll
            for (int nt = 0; nt < 4; ++nt)
                bf[nt] = *(const short8*)&Bs[(wn * 64 + nt * 16 + l16) * LSTR + kb * 32 + quad * 8];
#pragma unroll
            for (int mt = 0; mt < 4; ++mt)
#pragma unroll
                for (int nt = 0; nt < 4; ++nt)
                    acc[mt][nt] = __builtin_amdgcn_mfma_f32_16x16x32_bf16(
                        af[mt], bf[nt], acc[mt][nt], 0, 0, 0);
        }
    }

    // ---- fused projection epilogue (no h materialization, no atomics) ----
    // C/D layout: col = l16, row = quad*4 + reg (m89-verified).
    float* pr = (float*)Bs;                   // 64 rows x 4 outs = 1 KB
    __syncthreads();                          // all Bs reads done
    pr[tid] = 0.f;                            // 256 floats
    __syncthreads();

    const int cbase = wn * 64 + l16;
#pragma unroll
    for (int half = 0; half < 2; ++half) {
        const float* wA = half ? w2r : w2l;          // rows 0,1 of W2{l,r}
        f32x4 part[2][4];
#pragma unroll
        for (int c = 0; c < 2; ++c)
#pragma unroll
            for (int mt = 0; mt < 4; ++mt) part[c][mt] = (f32x4){0.f, 0.f, 0.f, 0.f};
#pragma unroll
        for (int nt = 0; nt < 4; ++nt) {
            const int col = cbase + nt * 16;
            const float bias = b1[col];
            const float w0 = wA[col];
            const float w1 = wA[HID_C + col];
#pragma unroll
            for (int mt = 0; mt < 4; ++mt)
#pragma unroll
                for (int r = 0; r < 4; ++r) {
                    float hv = fmaxf(acc[mt][nt][r] + bias, 0.0f);
                    part[0][mt][r] += hv * w0;
                    part[1][mt][r] += hv * w1;
                }
        }
#pragma unroll
        for (int c = 0; c < 2; ++c)
#pragma unroll
            for (int mt = 0; mt < 4; ++mt)
#pragma unroll
                for (int r = 0; r < 4; ++r)
#pragma unroll
                    for (int m = 1; m < 16; m <<= 1)
                        part[c][mt][r] += __shfl_xor(part[c][mt][r], m);
        if (l16 < 8) {
            const int ch2 = l16 & 1;
            const int mts = l16 >> 1;
#pragma unroll
            for (int r = 0; r < 4; ++r) {
                int rloc = quad * 4 + mts * 16 + r;    // 0..63
                atomicAdd(&pr[rloc * 4 + half * 2 + ch2], part[ch2][mts][r]);
            }
        }
    }
    __syncthreads();
    if (tid < 128) {
        int rloc = tid >> 1, pair = tid & 1;
        int row = row0 + rloc;
        if (row < nn) {
            float2 v = make_float2(pr[rloc * 4 + pair * 2],
                                   pr[rloc * 4 + pair * 2 + 1]);
            if (pair) rsg[row] = v; else p2g[row] = v;
        }
    }
}

// ---- Layer 2 tail: atomic-free per-segment aggregation + finalize ----------
// 512 thr / bucket; 4 threads per node split the sorted segment.

__global__ __launch_bounds__(512) void fin_bucket(
    const unsigned int* __restrict__ binned, const int* __restrict__ boffs,
    const int* __restrict__ deg,
    const float2* __restrict__ p2, const float2* __restrict__ rs,
    const float* __restrict__ b2, float* __restrict__ out, int n) {
    __shared__ float ps0[3][BKT_W];
    __shared__ float ps1[3][BKT_W];
    const int tid = threadIdx.x;
    const int ln = tid & (BKT_W - 1);
    const int hp = tid >> 7;               // 0..3
    const int bkt = blockIdx.x;
    const int node = bkt * BKT_W + ln;
    const unsigned short* sp =
        (const unsigned short*)(binned + (size_t)bkt * CAP);
    float s0 = 0.f, s1 = 0.f;
    int dg = 0;
    if (node < n) {
        int beg = boffs[node];
        dg = deg[node];
        int end = beg + dg;
        for (int i = beg + hp; i < end; i += 4) {
            float2 v = p2[sp[i]];
            s0 += v.x; s1 += v.y;
        }
    }
    if (hp) { ps0[hp - 1][ln] = s0; ps1[hp - 1][ln] = s1; }
    __syncthreads();
    if (!hp && node < n) {
        s0 += ps0[0][ln] + ps0[1][ln] + ps0[2][ln];
        s1 += ps1[0][ln] + ps1[1][ln] + ps1[2][ln];
        float inv = 1.0f / (float)max(dg, 1);
        float2 self = rs[node];
        out[node * 2 + 0] = s0 * inv + self.x + b2[0];
        out[node * 2 + 1] = s1 * inv + self.y + b2[1];
    }
}

// ---- launch ----------------------------------------------------------------

extern "C" void kernel_launch(void* const* d_in, const int* in_sizes, int n_in,
                              void* d_out, int out_size, void* d_ws, size_t ws_size,
                              hipStream_t stream) {
    const float* x   = (const float*)d_in[0];
    const int*   ei  = (const int*)d_in[1];
    const float* W1l = (const float*)d_in[2];
    const float* b1  = (const float*)d_in[3];
    const float* W1r = (const float*)d_in[4];
    const float* W2l = (const float*)d_in[5];
    const float* b2  = (const float*)d_in[6];
    const float* W2r = (const float*)d_in[7];
    float* out = (float*)d_out;

    const int N_ = in_sizes[0] / IN_C;      // 50000
    const int E_ = in_sizes[1] / 2;         // 800000
    const int nbkt = (N_ + BKT_W - 1) / BKT_W;   // 391

    char* wsb = (char*)d_ws;
    size_t off = 0;
    auto alloc = [&](size_t bytes) {
        void* ptr = wsb + off;
        off += ((bytes + 15) & ~(size_t)15);
        return ptr;
    };
    unsigned short* Abf = (unsigned short*)alloc((size_t)N_ * 256 * 2);  // 25.6 MB
    unsigned short* Bg  = (unsigned short*)alloc(256 * 256 * 2);         // 128 KB
    unsigned int* binned = (unsigned int*)alloc((size_t)(nbkt + 1) * CAP * 4); // 4.8 MB
    int*   bcnt = (int*)alloc(512 * 4);                                  // 2 KB
    float* p2f  = (float*)alloc((size_t)N_ * 2 * 4);                     // 400 KB
    float* rsf  = (float*)alloc((size_t)N_ * 2 * 4);                     // 400 KB
    int*   deg  = (int*)alloc((size_t)N_ * 4);
    int*   boffs = (int*)alloc((size_t)N_ * 4);
    // total ~31.9 MB

    const int xblk = (N_ * 32 + 511) / 512;           // 3125
    const int eblk = (E_ + 2047) / 2048;              // 391

    // dispatch 1: clear bucket cursors only (p2/rs plain-stored by gemm)
    hipMemsetAsync(bcnt, 0, 512 * sizeof(int), stream);

    // dispatch 2: fused conversions + coarse bucket scatter
    scatter_conv<<<xblk + 32 + eblk, 512, 0, stream>>>(
        x, (unsigned int*)Abf, W1l, W1r, Bg, ei, bcnt, binned,
        N_ * 32, xblk, E_);

    // dispatch 3: per-bucket sort + layer-1 neighbor gather (+ persist sorted)
    sort_gather<<<nbkt, 1024, 0, stream>>>(binned, bcnt, (const uint4*)Abf,
                                           (uint4*)Abf, deg, boffs, N_);

    // dispatch 4: full-row MFMA GEMM (A direct, B in LDS) + fused projection
    gemm1_fused<<<(N_ + 63) / 64, 256, 0, stream>>>(
        Abf, Bg, b1, W2l, W2r, (float2*)p2f, (float2*)rsf, N_);

    // dispatch 5: per-segment aggregate + finalize (no atomics)
    fin_bucket<<<nbkt, 512, 0, stream>>>(binned, boffs, deg,
                                         (const float2*)p2f, (const float2*)rsf,
                                         b2, out, N_);
}

// Round 8
// 177.683 us; speedup vs baseline: 1.2022x; 1.2022x over previous
//
#include <hip/hip_runtime.h>
#include <hip/hip_bf16.h>

// ---------------------------------------------------------------------------
// GraphSAGE 2-layer: h = relu(mean_agg(x) @ W1l^T + b1 + x @ W1r^T)
//                    out = mean_agg(h) @ W2l^T + b2 + h @ W2r^T
// N=50000, E=800000, C: 128 -> 256 -> 2.
// Session R7: R2-exact gemm K-loop + atomic-free epilogue.
//  WRITE_SIZE across R2/R5/R6 (45/81/109 MB) shows epilogue RMW/store
//  structure drives real HBM write traffic. This round: LDS cross-wave
//  combine (R1-validated mechanism, 2 KB in As) then PLAIN float2 stores
//  into disjoint per-block-y buffers p2[y*N+row], rs[y*N+row]. No global
//  atomics, no p2/rs memset (all entries written). fin_bucket sums the
//  two halves (both L2-resident, 800 KB each).
// Pipeline (5 dispatches): memset(bcnt, 2 KB) -> scatter_conv -> sort_gather
// -> gemm1_fused (391,2)x256thr -> fin_bucket.
// Failed-experiment ledger:
//  - R13(prev): 1024-thr GEMM, 62 KB LDS -> 2 blk/CU. Regressed.
//  - R14(prev): last-block-combines w/ __threadfence. Regressed hard.
//  - R1: 512-thr full-width GEMM, 55 KB LDS -> 2 blk/CU. 179.1 total (best;
//    its LDS-combine epilogue avoided atomic traffic -> reused here).
//  - R3/R4: reg-prefetch K-loop (VGPR 136 -> 3 waves/SIMD) + XCD swizzle:
//    182 -> 191. Reverted.
//  - R5: LDS-free direct-load gemm + atomics: 133 MB traffic, 209.6. Reverted.
//  - R6: full-row 64x256 gemm: B re-read 100 MB, WRITE 109 MB, 213.6. Reverted.
//  - Lesson: replay-pass durations distorted; WRITE traffic + totals are truth.
// ---------------------------------------------------------------------------

#define IN_C 128
#define HID_C 256
#define BKT_SHIFT 7
#define BKT_W 128            // dsts per bucket
#define CAP 3072             // bucket slot capacity (mean 2048, sigma 45)

typedef __attribute__((ext_vector_type(8))) short short8;   // 8 bf16 (4 VGPRs)
typedef __attribute__((ext_vector_type(4))) float f32x4;    // MFMA accumulator

static __device__ __forceinline__ unsigned short f2b(float f) {
    __hip_bfloat16 h = __float2bfloat16(f);
    return *(unsigned short*)&h;
}
static __device__ __forceinline__ float b2f(unsigned short u) {
    unsigned v = ((unsigned)u) << 16;
    return *(float*)&v;
}

// ---- fused conversions + direct bucket scatter -----------------------------
// Blocks [0, xblk): fill right half of A with bf16(x), float4->uint2.
// Blocks [xblk, xblk+32): Bg = bf16([W1l | W1r]), float4->ushort4.
// Blocks [xblk+32, ...): scatter 2048 edges/block into fixed bucket slots.
__global__ __launch_bounds__(512) void scatter_conv(
    const float* __restrict__ x, unsigned int* __restrict__ Abf,
    const float* __restrict__ w1l, const float* __restrict__ w1r,
    unsigned short* __restrict__ Bg,
    const int* __restrict__ ei, int* __restrict__ bcnt,
    unsigned int* __restrict__ binned,
    int nquads /* N*32 */, int xblk, int E_) {
    __shared__ int hist[512];
    __shared__ int lbase[512];
    const int tid = threadIdx.x;
    if (blockIdx.x < xblk) {
        int t = blockIdx.x * 512 + tid;          // one float4 (4 elems) per thr
        if (t >= nquads) return;
        float4 v = *(const float4*)&x[(size_t)t * 4];
        uint2 o;
        o.x = ((unsigned)f2b(v.y) << 16) | f2b(v.x);
        o.y = ((unsigned)f2b(v.w) << 16) | f2b(v.z);
        int node = t >> 5, g = t & 31;           // 32 quads per 128-float row
        *(uint2*)&Abf[(size_t)node * 128 + 64 + g * 2] = o;
    } else if (blockIdx.x < xblk + 32) {
        int idx4 = (blockIdx.x - xblk) * 512 + tid;   // 16384 float4 groups
        int o = idx4 >> 6, k4 = (idx4 & 63) * 4;
        const float* srcp = (k4 < IN_C) ? &w1l[o * IN_C + k4]
                                        : &w1r[o * IN_C + (k4 - IN_C)];
        float4 f = *(const float4*)srcp;
        ushort4 s;
        s.x = f2b(f.x); s.y = f2b(f.y); s.z = f2b(f.z); s.w = f2b(f.w);
        *(ushort4*)&Bg[(size_t)idx4 * 4] = s;
    } else {
        const int e0 = (blockIdx.x - xblk - 32) * 2048;
        hist[tid] = 0;
        __syncthreads();
        int dreg[4];
#pragma unroll
        for (int j = 0; j < 4; ++j) {
            int e = e0 + j * 512 + tid;
            dreg[j] = (e < E_) ? ei[E_ + e] : -1;
            if (dreg[j] >= 0) atomicAdd(&hist[dreg[j] >> BKT_SHIFT], 1);
        }
        __syncthreads();
        {
            int c = hist[tid];
            lbase[tid] = c ? tid * CAP + atomicAdd(&bcnt[tid], c) : 0;
            hist[tid] = 0;   // reuse as local cursor
        }
        __syncthreads();
#pragma unroll
        for (int j = 0; j < 4; ++j) {
            int e = e0 + j * 512 + tid;
            if (dreg[j] >= 0) {
                int d = dreg[j];
                int b = d >> BKT_SHIFT;
                int pos = lbase[b] + atomicAdd(&hist[b], 1);
                if (pos < b * CAP + CAP)   // +22 sigma guard, never taken
                    binned[pos] = ((unsigned)ei[e] << BKT_SHIFT) |
                                  (unsigned)(d & (BKT_W - 1));
            }
        }
    }
}

// ---- per-bucket LDS sort + immediate neighbor gather -----------------------
// Also persists the sorted src list (ushort, in-place over binned) and the
// per-node segment offsets for the atomic-free fin_bucket.

__global__ __launch_bounds__(1024) void sort_gather(
    unsigned int* __restrict__ binned, const int* __restrict__ bcnt,
    const uint4* __restrict__ abf4c, uint4* __restrict__ Abf4,
    int* __restrict__ deg, int* __restrict__ boffs, int n) {
    __shared__ unsigned int ebuf[CAP];        // 12 KB
    __shared__ unsigned short sbuf[CAP];      // 6 KB
    __shared__ int hist[BKT_W];
    __shared__ int offs[BKT_W];
    __shared__ int cur[BKT_W];
    const int tid = threadIdx.x;
    const int lane = tid & 63;
    const int bkt = blockIdx.x;
    const int gbase = bkt * CAP;
    int cnt = bcnt[bkt];
    if (cnt > CAP) cnt = CAP;

    if (tid < BKT_W) hist[tid] = 0;
    {   // vectorized ebuf fill (binned+gbase is 16B aligned: CAP*4 = 12 KB)
        const int cnt4 = cnt >> 2;
        const uint4* b4 = (const uint4*)(binned + gbase);
        uint4* e4 = (uint4*)ebuf;
        for (int i = tid; i < cnt4; i += 1024) e4[i] = b4[i];
        for (int i = cnt4 * 4 + tid; i < cnt; i += 1024)
            ebuf[i] = binned[gbase + i];
    }
    __syncthreads();
    for (int i = tid; i < cnt; i += 1024)
        atomicAdd(&hist[ebuf[i] & (BKT_W - 1)], 1);
    __syncthreads();
    if (tid < 64) {   // single-wave scan of 128 counts, 2/lane
        int h0 = hist[lane * 2], h1 = hist[lane * 2 + 1];
        int s = h0 + h1;
        int incl = s;
#pragma unroll
        for (int off = 1; off < 64; off <<= 1) {
            int t = __shfl_up(incl, off);
            if (lane >= off) incl += t;
        }
        int excl = incl - s;
        offs[lane * 2] = excl;          cur[lane * 2] = excl;
        offs[lane * 2 + 1] = excl + h0; cur[lane * 2 + 1] = excl + h0;
    }
    __syncthreads();
    for (int i = tid; i < cnt; i += 1024) {
        unsigned int pk = ebuf[i];
        int pos = atomicAdd(&cur[pk & (BKT_W - 1)], 1);
        sbuf[pos] = (unsigned short)(pk >> BKT_SHIFT);   // src (< 65536)
    }
    if (tid < BKT_W) {
        int node = bkt * BKT_W + tid;
        if (node < n) { deg[node] = hist[tid]; boffs[node] = offs[tid]; }
    }
    __syncthreads();

    // persist sorted src list over our own (fully consumed) binned region;
    // packed 2 ushorts per 4B store. Overlaps with the gather phase below.
    {
        unsigned int* so = (unsigned int*)(binned + gbase);
        const int half = (cnt + 1) >> 1;
        for (int i = tid; i < half; i += 1024) {
            unsigned lo = sbuf[i * 2];
            unsigned hi = (i * 2 + 1 < cnt) ? sbuf[i * 2 + 1] : 0u;
            so[i] = lo | (hi << 16);
        }
    }

    // gather phase: wave wv handles local dsts [wv*8, wv*8+8)
    const int wv = tid >> 6;
    const int ep = lane >> 4;
    const int pos = lane & 15;
    for (int ld = wv * 8; ld < wv * 8 + 8; ++ld) {
        int node = bkt * BKT_W + ld;
        if (node >= n) break;
        int beg = offs[ld], end = offs[ld] + hist[ld];
        float s[8] = {0.f, 0.f, 0.f, 0.f, 0.f, 0.f, 0.f, 0.f};
        for (int e = beg; e < end; e += 16) {
#pragma unroll
            for (int g = 0; g < 4; ++g) {       // 4 uint4 loads in flight
                int eg = e + g * 4 + ep;
                if (eg < end) {
                    int src = sbuf[eg];
                    // right half of Abf row (== bf16(x) for this src)
                    uint4 u = abf4c[(size_t)src * 32 + 16 + pos];
                    s[0] += b2f(u.x & 0xffff); s[1] += b2f(u.x >> 16);
                    s[2] += b2f(u.y & 0xffff); s[3] += b2f(u.y >> 16);
                    s[4] += b2f(u.z & 0xffff); s[5] += b2f(u.z >> 16);
                    s[6] += b2f(u.w & 0xffff); s[7] += b2f(u.w >> 16);
                }
            }
        }
#pragma unroll
        for (int i = 0; i < 8; ++i) {
            s[i] += __shfl_xor(s[i], 16);
            s[i] += __shfl_xor(s[i], 32);
        }
        if (ep == 0) {
            float inv = 1.0f / (float)max(end - beg, 1);
            uint4 o;
            o.x = ((unsigned)f2b(s[1] * inv) << 16) | f2b(s[0] * inv);
            o.y = ((unsigned)f2b(s[3] * inv) << 16) | f2b(s[2] * inv);
            o.z = ((unsigned)f2b(s[5] * inv) << 16) | f2b(s[4] * inv);
            o.w = ((unsigned)f2b(s[7] * inv) << 16) | f2b(s[6] * inv);
            Abf4[(size_t)node * 32 + pos] = o;   // left half of A row
        }
    }
}

// ---- Layer-1 GEMM + fused layer-2 projection -------------------------------
// R2-exact K-loop: 256 thr, 128x128 tile, grid (391,2), 36 KB LDS, 4 blk/CU.
// Epilogue: per-wave shuffle reduce -> LDS pr combine (reusing As, 2 KB) ->
// PLAIN float2 stores to p2[y*stride+row] / rs[y*stride+row]. No atomics.

#define LSTR 72

__global__ __launch_bounds__(256) void gemm1_fused(
    const unsigned short* __restrict__ Abf, const unsigned short* __restrict__ Bg,
    const float* __restrict__ b1, const float* __restrict__ w2l,
    const float* __restrict__ w2r, float2* __restrict__ p2g,
    float2* __restrict__ rsg, int nn) {
    __shared__ short As[128 * LSTR];
    __shared__ short Bs[128 * LSTR];

    const int tid = threadIdx.x;
    const int lane = tid & 63;
    const int wid = tid >> 6;
    const int wm = wid >> 1, wn = wid & 1;
    const int row0 = blockIdx.x * 128;
    const int col0 = blockIdx.y * 128;

    const int srow = tid >> 1;
    const int skc = (tid & 1) * 32;
    int arow = row0 + srow;
    if (arow >= nn) arow = nn - 1;
    const size_t agoff = (size_t)arow * 256 + skc;
    const size_t bgoff = (size_t)(col0 + srow) * 256 + skc;

    f32x4 acc[4][4];
#pragma unroll
    for (int i = 0; i < 4; ++i)
#pragma unroll
        for (int j = 0; j < 4; ++j) acc[i][j] = (f32x4){0.f, 0.f, 0.f, 0.f};

    const int quad = lane >> 4;     // 0..3
    const int l16 = lane & 15;

    for (int k0 = 0; k0 < 256; k0 += 64) {
        const uint4* ga = (const uint4*)(Abf + agoff + k0);
        const uint4* gb = (const uint4*)(Bg + bgoff + k0);
        uint4 va0 = ga[0], va1 = ga[1], va2 = ga[2], va3 = ga[3];
        uint4 vb0 = gb[0], vb1 = gb[1], vb2 = gb[2], vb3 = gb[3];

        __syncthreads();
        uint4* la = (uint4*)&As[srow * LSTR + skc];
        uint4* lb = (uint4*)&Bs[srow * LSTR + skc];
        la[0] = va0; la[1] = va1; la[2] = va2; la[3] = va3;
        lb[0] = vb0; lb[1] = vb1; lb[2] = vb2; lb[3] = vb3;
        __syncthreads();

#pragma unroll
        for (int kb = 0; kb < 2; ++kb) {
            short8 af[4], bf[4];
#pragma unroll
            for (int mt = 0; mt < 4; ++mt)
                af[mt] = *(const short8*)&As[(wm * 64 + mt * 16 + l16) * LSTR + kb * 32 + quad * 8];
#pragma unroll
            for (int nt = 0; nt < 4; ++nt)
                bf[nt] = *(const short8*)&Bs[(wn * 64 + nt * 16 + l16) * LSTR + kb * 32 + quad * 8];
#pragma unroll
            for (int mt = 0; mt < 4; ++mt)
#pragma unroll
                for (int nt = 0; nt < 4; ++nt)
                    acc[mt][nt] = __builtin_amdgcn_mfma_f32_16x16x32_bf16(
                        af[mt], bf[nt], acc[mt][nt], 0, 0, 0);
        }
    }

    // ---- fused projection epilogue (no h materialization, no atomics) ----
    // C/D layout: col = l16, row = quad*4 + reg (m89-verified).
    // Per-wave 16-lane shuffle reduce -> LDS pr[128][4] combine across the
    // two wn waves -> plain float2 stores into the blockIdx.y slice.
    float* pr = (float*)As;                    // 128 rows x 4 outs = 2 KB
    __syncthreads();                           // all As/Bs MFMA reads done
    pr[tid] = 0.f; pr[tid + 256] = 0.f;        // 512 floats
    __syncthreads();

    const int cbase = col0 + wn * 64 + l16;
#pragma unroll
    for (int half = 0; half < 2; ++half) {
        const float* wA = half ? w2r : w2l;          // rows 0,1 of W2{l,r}
        f32x4 part[2][4];
#pragma unroll
        for (int c = 0; c < 2; ++c)
#pragma unroll
            for (int mt = 0; mt < 4; ++mt) part[c][mt] = (f32x4){0.f, 0.f, 0.f, 0.f};
#pragma unroll
        for (int nt = 0; nt < 4; ++nt) {
            const int col = cbase + nt * 16;
            const float bias = b1[col];
            const float w0 = wA[col];
            const float w1 = wA[HID_C + col];
#pragma unroll
            for (int mt = 0; mt < 4; ++mt)
#pragma unroll
                for (int r = 0; r < 4; ++r) {
                    float hv = fmaxf(acc[mt][nt][r] + bias, 0.0f);
                    part[0][mt][r] += hv * w0;
                    part[1][mt][r] += hv * w1;
                }
        }
#pragma unroll
        for (int c = 0; c < 2; ++c)
#pragma unroll
            for (int mt = 0; mt < 4; ++mt)
#pragma unroll
                for (int r = 0; r < 4; ++r)
#pragma unroll
                    for (int m = 1; m < 16; m <<= 1)
                        part[c][mt][r] += __shfl_xor(part[c][mt][r], m);
        if (l16 < 8) {
            const int ch2 = l16 & 1;
            const int mts = l16 >> 1;
#pragma unroll
            for (int r = 0; r < 4; ++r) {
                int rloc = wm * 64 + quad * 4 + mts * 16 + r;   // 0..127
                atomicAdd(&pr[rloc * 4 + half * 2 + ch2], part[ch2][mts][r]);
            }
        }
    }
    __syncthreads();
    if (tid < 256) {   // 128 rows x {p2, rs}
        int rloc = tid >> 1, pair = tid & 1;
        int row = row0 + rloc;
        if (row < nn) {
            float2 v = make_float2(pr[rloc * 4 + pair * 2],
                                   pr[rloc * 4 + pair * 2 + 1]);
            size_t idx = (size_t)blockIdx.y * nn + row;
            if (pair) rsg[idx] = v; else p2g[idx] = v;
        }
    }
}

// ---- Layer 2 tail: atomic-free per-segment aggregation + finalize ----------
// 512 thr / bucket; 4 threads per node split the sorted segment.
// p2/rs each have two disjoint halves (blockIdx.y slices) -> sum both.

__global__ __launch_bounds__(512) void fin_bucket(
    const unsigned int* __restrict__ binned, const int* __restrict__ boffs,
    const int* __restrict__ deg,
    const float2* __restrict__ p2, const float2* __restrict__ rs,
    const float* __restrict__ b2, float* __restrict__ out, int n) {
    __shared__ float ps0[3][BKT_W];
    __shared__ float ps1[3][BKT_W];
    const int tid = threadIdx.x;
    const int ln = tid & (BKT_W - 1);
    const int hp = tid >> 7;               // 0..3
    const int bkt = blockIdx.x;
    const int node = bkt * BKT_W + ln;
    const unsigned short* sp =
        (const unsigned short*)(binned + (size_t)bkt * CAP);
    float s0 = 0.f, s1 = 0.f;
    int dg = 0;
    if (node < n) {
        int beg = boffs[node];
        dg = deg[node];
        int end = beg + dg;
        for (int i = beg + hp; i < end; i += 4) {
            int s = sp[i];
            float2 va = p2[s];
            float2 vb = p2[n + s];
            s0 += va.x + vb.x; s1 += va.y + vb.y;
        }
    }
    if (hp) { ps0[hp - 1][ln] = s0; ps1[hp - 1][ln] = s1; }
    __syncthreads();
    if (!hp && node < n) {
        s0 += ps0[0][ln] + ps0[1][ln] + ps0[2][ln];
        s1 += ps1[0][ln] + ps1[1][ln] + ps1[2][ln];
        float inv = 1.0f / (float)max(dg, 1);
        float2 sa = rs[node], sb = rs[n + node];
        out[node * 2 + 0] = s0 * inv + sa.x + sb.x + b2[0];
        out[node * 2 + 1] = s1 * inv + sa.y + sb.y + b2[1];
    }
}

// ---- launch ----------------------------------------------------------------

extern "C" void kernel_launch(void* const* d_in, const int* in_sizes, int n_in,
                              void* d_out, int out_size, void* d_ws, size_t ws_size,
                              hipStream_t stream) {
    const float* x   = (const float*)d_in[0];
    const int*   ei  = (const int*)d_in[1];
    const float* W1l = (const float*)d_in[2];
    const float* b1  = (const float*)d_in[3];
    const float* W1r = (const float*)d_in[4];
    const float* W2l = (const float*)d_in[5];
    const float* b2  = (const float*)d_in[6];
    const float* W2r = (const float*)d_in[7];
    float* out = (float*)d_out;

    const int N_ = in_sizes[0] / IN_C;      // 50000
    const int E_ = in_sizes[1] / 2;         // 800000
    const int nbkt = (N_ + BKT_W - 1) / BKT_W;   // 391

    char* wsb = (char*)d_ws;
    size_t off = 0;
    auto alloc = [&](size_t bytes) {
        void* ptr = wsb + off;
        off += ((bytes + 15) & ~(size_t)15);
        return ptr;
    };
    unsigned short* Abf = (unsigned short*)alloc((size_t)N_ * 256 * 2);  // 25.6 MB
    unsigned short* Bg  = (unsigned short*)alloc(256 * 256 * 2);         // 128 KB
    unsigned int* binned = (unsigned int*)alloc((size_t)(nbkt + 1) * CAP * 4); // 4.8 MB
    int*   bcnt = (int*)alloc(512 * 4);                                  // 2 KB
    float* p2f  = (float*)alloc((size_t)N_ * 2 * 2 * 4);                 // 800 KB (2 slices)
    float* rsf  = (float*)alloc((size_t)N_ * 2 * 2 * 4);                 // 800 KB (2 slices)
    int*   deg  = (int*)alloc((size_t)N_ * 4);
    int*   boffs = (int*)alloc((size_t)N_ * 4);
    // total ~32.7 MB

    const int xblk = (N_ * 32 + 511) / 512;           // 3125
    const int eblk = (E_ + 2047) / 2048;              // 391

    // dispatch 1: clear bucket cursors only (p2/rs fully written by gemm)
    hipMemsetAsync(bcnt, 0, 512 * sizeof(int), stream);

    // dispatch 2: fused conversions + coarse bucket scatter
    scatter_conv<<<xblk + 32 + eblk, 512, 0, stream>>>(
        x, (unsigned int*)Abf, W1l, W1r, Bg, ei, bcnt, binned,
        N_ * 32, xblk, E_);

    // dispatch 3: per-bucket sort + layer-1 neighbor gather (+ persist sorted)
    sort_gather<<<nbkt, 1024, 0, stream>>>(binned, bcnt, (const uint4*)Abf,
                                           (uint4*)Abf, deg, boffs, N_);

    // dispatch 4: MFMA GEMM + fused projection -> disjoint slice stores
    gemm1_fused<<<dim3((N_ + 127) / 128, 2), 256, 0, stream>>>(
        Abf, Bg, b1, W2l, W2r, (float2*)p2f, (float2*)rsf, N_);

    // dispatch 5: per-segment aggregate (sums both slices) + finalize
    fin_bucket<<<nbkt, 512, 0, stream>>>(binned, boffs, deg,
                                         (const float2*)p2f, (const float2*)rsf,
                                         b2, out, N_);
}